// Round 1
// baseline (65.552 us; speedup 1.0000x reference)
//
#include <hip/hip_runtime.h>
#include <math.h>

// 180 / pi
#define FACTOR 57.29577951308232f

// x: [npts, 3] fp32 cartesian -> out: [npts, 2] fp32 (phi, psi) in degrees.
// phi = -(acos(z/|r|)*FACTOR + 15),  psi = sign(y)*acos(x/|r_xy|)*FACTOR
__device__ __forceinline__ void point_to_angles(float X, float Y, float Z,
                                                float& phi_out, float& psi_out) {
    float n2   = fmaf(X, X, fmaf(Y, Y, Z * Z));
    float nxy2 = fmaf(X, X, Y * Y);
    float nf   = sqrtf(n2);
    float nxy  = sqrtf(nxy2);
    // clamp to [-1,1]: fp32 rounding can push |arg| past 1 -> acos NaN
    float ca = fminf(fmaxf(Z / nf, -1.0f), 1.0f);
    float cb = fminf(fmaxf(X / nxy, -1.0f), 1.0f);
    float phi = acosf(ca);
    float psi = acosf(cb);
    psi = (Y < 0.0f) ? -psi : psi;
    phi_out = -fmaf(phi, FACTOR, 15.0f);
    psi_out = psi * FACTOR;
}

__global__ __launch_bounds__(256) void SpLayer_57707180589153_kernel(
    const float* __restrict__ x, float* __restrict__ out,
    int ngroups, long long npts) {
    int t = blockIdx.x * blockDim.x + threadIdx.x;
    if (t >= ngroups) return;

    long long p0 = 4LL * t;
    if (p0 + 4 <= npts) {
        // fast path: 4 points = 12 floats = 3x float4 loads
        const float4* in4 = reinterpret_cast<const float4*>(x);
        float4 a = in4[3LL * t + 0];
        float4 b = in4[3LL * t + 1];
        float4 c = in4[3LL * t + 2];

        float px[4] = {a.x, a.w, b.z, c.y};
        float py[4] = {a.y, b.x, b.w, c.z};
        float pz[4] = {a.z, b.y, c.x, c.w};

        float res[8];
        #pragma unroll
        for (int i = 0; i < 4; ++i) {
            point_to_angles(px[i], py[i], pz[i], res[2 * i], res[2 * i + 1]);
        }

        float4* o4 = reinterpret_cast<float4*>(out);
        o4[2LL * t + 0] = make_float4(res[0], res[1], res[2], res[3]);
        o4[2LL * t + 1] = make_float4(res[4], res[5], res[6], res[7]);
    } else {
        // scalar tail
        for (long long p = p0; p < npts; ++p) {
            float X = x[3 * p + 0];
            float Y = x[3 * p + 1];
            float Z = x[3 * p + 2];
            float phi, psi;
            point_to_angles(X, Y, Z, phi, psi);
            out[2 * p + 0] = phi;
            out[2 * p + 1] = psi;
        }
    }
}

extern "C" void kernel_launch(void* const* d_in, const int* in_sizes, int n_in,
                              void* d_out, int out_size, void* d_ws, size_t ws_size,
                              hipStream_t stream) {
    const float* x = (const float*)d_in[0];
    float* out = (float*)d_out;

    long long npts = (long long)in_sizes[0] / 3;   // 16,777,216
    int ngroups = (int)((npts + 3) / 4);           // 4 points per thread

    const int block = 256;
    int grid = (ngroups + block - 1) / block;
    SpLayer_57707180589153_kernel<<<grid, block, 0, stream>>>(x, out, ngroups, npts);
}

// Round 2
// 64.282 us; speedup vs baseline: 1.0198x; 1.0198x over previous
//
#include <hip/hip_runtime.h>
#include <math.h>

// acos in DEGREES via A&S 4.4.45 minimax, coefficients pre-multiplied by 180/pi.
// acos_deg(|x|) = sqrt(1-|x|) * P(|x|), |poly err| ~2e-8 rad << 3.9 deg threshold.
__device__ __forceinline__ float acos_deg_abs(float ax) {
    float p = fmaf(ax, -0.0723345f, 0.3821680f);
    p = fmaf(ax, p, -0.9790775f);
    p = fmaf(ax, p, 1.7699747f);
    p = fmaf(ax, p, -2.8747760f);
    p = fmaf(ax, p, 5.0981200f);
    p = fmaf(ax, p, -12.2956049f);
    p = fmaf(ax, p, 90.0f);
    float s = __builtin_amdgcn_sqrtf(1.0f - ax);   // raw v_sqrt_f32
    return s * p;
}

__device__ __forceinline__ float acos_deg(float c) {
    float ax = fminf(fabsf(c), 1.0f);              // clamp guards rsq rounding >1
    float r = acos_deg_abs(ax);
    return (c < 0.0f) ? (180.0f - r) : r;          // acos(-x) = 180 - acos(x)
}

// phi = -(acos_deg(z/|r|) + 15),  psi = sign(y)*acos_deg(x/|r_xy|)
__device__ __forceinline__ void point_to_angles(float X, float Y, float Z,
                                                float& phi_out, float& psi_out) {
    float sxy = fmaf(X, X, Y * Y);
    float n2  = fmaf(Z, Z, sxy);
    float ca = Z * __builtin_amdgcn_rsqf(n2);      // raw v_rsq_f32, no IEEE div
    float cb = X * __builtin_amdgcn_rsqf(sxy);
    float aphi = acos_deg(ca);
    float apsi = acos_deg(cb);
    phi_out = -aphi - 15.0f;
    psi_out = (Y < 0.0f) ? -apsi : apsi;
}

__global__ __launch_bounds__(256) void SpLayer_57707180589153_kernel(
    const float* __restrict__ x, float* __restrict__ out,
    int ngroups, long long npts) {
    int t = blockIdx.x * blockDim.x + threadIdx.x;
    if (t >= ngroups) return;

    long long p0 = 4LL * t;
    if (p0 + 4 <= npts) {
        // fast path: 4 points = 12 floats = 3x float4 loads
        const float4* in4 = reinterpret_cast<const float4*>(x);
        float4 a = in4[3LL * t + 0];
        float4 b = in4[3LL * t + 1];
        float4 c = in4[3LL * t + 2];

        float px[4] = {a.x, a.w, b.z, c.y};
        float py[4] = {a.y, b.x, b.w, c.z};
        float pz[4] = {a.z, b.y, c.x, c.w};

        float res[8];
        #pragma unroll
        for (int i = 0; i < 4; ++i) {
            point_to_angles(px[i], py[i], pz[i], res[2 * i], res[2 * i + 1]);
        }

        float4* o4 = reinterpret_cast<float4*>(out);
        o4[2LL * t + 0] = make_float4(res[0], res[1], res[2], res[3]);
        o4[2LL * t + 1] = make_float4(res[4], res[5], res[6], res[7]);
    } else {
        // scalar tail
        for (long long p = p0; p < npts; ++p) {
            float X = x[3 * p + 0];
            float Y = x[3 * p + 1];
            float Z = x[3 * p + 2];
            float phi, psi;
            point_to_angles(X, Y, Z, phi, psi);
            out[2 * p + 0] = phi;
            out[2 * p + 1] = psi;
        }
    }
}

extern "C" void kernel_launch(void* const* d_in, const int* in_sizes, int n_in,
                              void* d_out, int out_size, void* d_ws, size_t ws_size,
                              hipStream_t stream) {
    const float* x = (const float*)d_in[0];
    float* out = (float*)d_out;

    long long npts = (long long)in_sizes[0] / 3;   // 16,777,216
    int ngroups = (int)((npts + 3) / 4);           // 4 points per thread

    const int block = 256;
    int grid = (ngroups + block - 1) / block;
    SpLayer_57707180589153_kernel<<<grid, block, 0, stream>>>(x, out, ngroups, npts);
}

// Round 3
// 62.712 us; speedup vs baseline: 1.0453x; 1.0250x over previous
//
#include <hip/hip_runtime.h>
#include <math.h>

// acos in DEGREES via A&S 4.4.45-style minimax, coefficients pre-scaled by 180/pi.
// acos_deg(|x|) = sqrt(1-|x|) * P(|x|)
__device__ __forceinline__ float acos_deg_abs(float ax) {
    float p = fmaf(ax, -0.0723345f, 0.3821680f);
    p = fmaf(ax, p, -0.9790775f);
    p = fmaf(ax, p, 1.7699747f);
    p = fmaf(ax, p, -2.8747760f);
    p = fmaf(ax, p, 5.0981200f);
    p = fmaf(ax, p, -12.2956049f);
    p = fmaf(ax, p, 90.0f);
    float s = __builtin_amdgcn_sqrtf(1.0f - ax);   // raw v_sqrt_f32
    return s * p;
}

__device__ __forceinline__ float acos_deg(float c) {
    float ax = fminf(fabsf(c), 1.0f);              // clamp guards rsq rounding >1
    float r = acos_deg_abs(ax);
    return (c < 0.0f) ? (180.0f - r) : r;          // acos(-x) = 180 - acos(x)
}

// phi = -(acos_deg(z/|r|) + 15),  psi = sign(y)*acos_deg(x/|r_xy|)
__device__ __forceinline__ void point_to_angles(float X, float Y, float Z,
                                                float& phi_out, float& psi_out) {
    float sxy = fmaf(X, X, Y * Y);
    float n2  = fmaf(Z, Z, sxy);
    float ca = Z * __builtin_amdgcn_rsqf(n2);      // raw v_rsq_f32, no IEEE div
    float cb = X * __builtin_amdgcn_rsqf(sxy);
    float aphi = acos_deg(ca);
    float apsi = acos_deg(cb);
    phi_out = -aphi - 15.0f;
    psi_out = (Y < 0.0f) ? -apsi : apsi;
}

#define PTS_PER_BLOCK 1024   // 256 threads x 4 points; 12 KB LDS tile

__global__ __launch_bounds__(256) void SpLayer_57707180589153_kernel(
    const float* __restrict__ x, float* __restrict__ out, long long npts) {
    __shared__ float tile[3 * PTS_PER_BLOCK];
    const int tid = threadIdx.x;
    const long long base = (long long)blockIdx.x * PTS_PER_BLOCK;

    if (base + PTS_PER_BLOCK <= npts) {
        // Stage: 3 block-stride float4 loads, each instruction contiguous 4KB.
        const float4* in4 = reinterpret_cast<const float4*>(x + base * 3);
        float4* t4 = reinterpret_cast<float4*>(tile);
        #pragma unroll
        for (int k = 0; k < 3; ++k)
            t4[k * 256 + tid] = in4[k * 256 + tid];
        __syncthreads();

        // Consume: 4 block-stride points per thread; LDS lane stride 12B
        // -> word idx 3*tid mod 32 -> only 2-way aliasing (free).
        float2* o2 = reinterpret_cast<float2*>(out) + base;
        #pragma unroll
        for (int j = 0; j < 4; ++j) {
            int p = j * 256 + tid;
            float X = tile[3 * p + 0];
            float Y = tile[3 * p + 1];
            float Z = tile[3 * p + 2];
            float phi, psi;
            point_to_angles(X, Y, Z, phi, psi);
            o2[p] = make_float2(phi, psi);   // contiguous 2KB per instruction
        }
    } else {
        // tail block: scalar, bounds-checked
        for (long long p = base + tid; p < npts; p += 256) {
            float X = x[3 * p + 0];
            float Y = x[3 * p + 1];
            float Z = x[3 * p + 2];
            float phi, psi;
            point_to_angles(X, Y, Z, phi, psi);
            out[2 * p + 0] = phi;
            out[2 * p + 1] = psi;
        }
    }
}

extern "C" void kernel_launch(void* const* d_in, const int* in_sizes, int n_in,
                              void* d_out, int out_size, void* d_ws, size_t ws_size,
                              hipStream_t stream) {
    const float* x = (const float*)d_in[0];
    float* out = (float*)d_out;

    long long npts = (long long)in_sizes[0] / 3;   // 16,777,216
    long long nblocks = (npts + PTS_PER_BLOCK - 1) / PTS_PER_BLOCK;

    SpLayer_57707180589153_kernel<<<(int)nblocks, 256, 0, stream>>>(x, out, npts);
}

// Round 5
// 54.982 us; speedup vs baseline: 1.1922x; 1.1406x over previous
//
#include <hip/hip_runtime.h>
#include <math.h>

typedef float floatx4 __attribute__((ext_vector_type(4)));  // native vec for nt builtins

// acos in DEGREES via A&S 4.4.45-style minimax, coefficients pre-scaled by 180/pi.
// acos_deg(|x|) = sqrt(1-|x|) * P(|x|)
__device__ __forceinline__ float acos_deg_abs(float ax) {
    float p = fmaf(ax, -0.0723345f, 0.3821680f);
    p = fmaf(ax, p, -0.9790775f);
    p = fmaf(ax, p, 1.7699747f);
    p = fmaf(ax, p, -2.8747760f);
    p = fmaf(ax, p, 5.0981200f);
    p = fmaf(ax, p, -12.2956049f);
    p = fmaf(ax, p, 90.0f);
    float s = __builtin_amdgcn_sqrtf(1.0f - ax);   // raw v_sqrt_f32
    return s * p;
}

__device__ __forceinline__ float acos_deg(float c) {
    float ax = fminf(fabsf(c), 1.0f);              // clamp guards rsq rounding >1
    float r = acos_deg_abs(ax);
    return (c < 0.0f) ? (180.0f - r) : r;          // acos(-x) = 180 - acos(x)
}

// phi = -(acos_deg(z/|r|) + 15),  psi = sign(y)*acos_deg(x/|r_xy|)
__device__ __forceinline__ void point_to_angles(float X, float Y, float Z,
                                                float& phi_out, float& psi_out) {
    float sxy = fmaf(X, X, Y * Y);
    float n2  = fmaf(Z, Z, sxy);
    float ca = Z * __builtin_amdgcn_rsqf(n2);      // raw v_rsq_f32, no IEEE div
    float cb = X * __builtin_amdgcn_rsqf(sxy);
    float aphi = acos_deg(ca);
    float apsi = acos_deg(cb);
    phi_out = -aphi - 15.0f;
    psi_out = (Y < 0.0f) ? -apsi : apsi;
}

#define PTS_PER_BLOCK 1024   // 256 threads x 4 points; 12 KB LDS tile

__global__ __launch_bounds__(256) void SpLayer_57707180589153_kernel(
    const float* __restrict__ x, float* __restrict__ out, long long npts) {
    __shared__ float tile[3 * PTS_PER_BLOCK];
    const int tid = threadIdx.x;
    const long long base = (long long)blockIdx.x * PTS_PER_BLOCK;

    if (base + PTS_PER_BLOCK <= npts) {
        // Stage: 3 block-stride nontemporal float4 loads, each instruction
        // a contiguous 4KB slab (per-wave 1KiB segments).
        const floatx4* in4 = reinterpret_cast<const floatx4*>(x + base * 3);
        floatx4* t4 = reinterpret_cast<floatx4*>(tile);
        #pragma unroll
        for (int k = 0; k < 3; ++k)
            t4[k * 256 + tid] = __builtin_nontemporal_load(&in4[k * 256 + tid]);
        __syncthreads();

        // Consume: each thread owns 2 consecutive points in each of 2 sub-tiles
        // -> one float4 (2 points) nontemporal store per sub-tile.
        floatx4* o4 = reinterpret_cast<floatx4*>(out) + base / 2;
        #pragma unroll
        for (int j = 0; j < 2; ++j) {
            int q = j * 256 + tid;      // pair index within block tile
            float r[4];
            #pragma unroll
            for (int s = 0; s < 2; ++s) {
                int p = 2 * q + s;
                float X = tile[3 * p + 0];
                float Y = tile[3 * p + 1];
                float Z = tile[3 * p + 2];
                point_to_angles(X, Y, Z, r[2 * s], r[2 * s + 1]);
            }
            floatx4 v = {r[0], r[1], r[2], r[3]};
            __builtin_nontemporal_store(v, &o4[q]);
        }
    } else {
        // tail block: scalar, bounds-checked
        for (long long p = base + tid; p < npts; p += 256) {
            float X = x[3 * p + 0];
            float Y = x[3 * p + 1];
            float Z = x[3 * p + 2];
            float phi, psi;
            point_to_angles(X, Y, Z, phi, psi);
            out[2 * p + 0] = phi;
            out[2 * p + 1] = psi;
        }
    }
}

extern "C" void kernel_launch(void* const* d_in, const int* in_sizes, int n_in,
                              void* d_out, int out_size, void* d_ws, size_t ws_size,
                              hipStream_t stream) {
    const float* x = (const float*)d_in[0];
    float* out = (float*)d_out;

    long long npts = (long long)in_sizes[0] / 3;   // 16,777,216
    long long nblocks = (npts + PTS_PER_BLOCK - 1) / PTS_PER_BLOCK;

    SpLayer_57707180589153_kernel<<<(int)nblocks, 256, 0, stream>>>(x, out, npts);
}